// Round 5
// baseline (199.019 us; speedup 1.0000x reference)
//
#include <hip/hip_runtime.h>
#include <cstddef>

typedef __attribute__((ext_vector_type(8))) short bf16x8;
typedef __attribute__((ext_vector_type(4))) float f32x4;

#define MFMA(a, b, c) __builtin_amdgcn_mfma_f32_16x16x32_bf16((a), (b), (c), 0, 0, 0)

static __device__ __forceinline__ unsigned short f2bf(float f) {
  unsigned u = __builtin_bit_cast(unsigned, f);
  u = u + 0x7FFFu + ((u >> 16) & 1u);
  return (unsigned short)(u >> 16);
}
static __device__ __forceinline__ float bf2f(unsigned short h) {
  unsigned u = ((unsigned)h) << 16;
  return __builtin_bit_cast(float, u);
}
static __device__ __forceinline__ float fast_sig(float x) {
  return __builtin_amdgcn_rcpf(1.0f + __expf(-x));
}
static __device__ __forceinline__ float fast_tanh(float x) {
  return 2.0f * __builtin_amdgcn_rcpf(1.0f + __expf(-2.0f * x)) - 1.0f;
}

// Activation buffer: [16 batch rows][256 B = 128 bf16 k-slots], XOR-swizzled per row.
// B-fragment (cols = batch): lane holds col b=lane&15, k = kc*32 + (lane>>4)*8 + {0..7}.
static __device__ __forceinline__ bf16x8 aread(const char* base, int lane, int kc) {
  int b = lane & 15, g = lane >> 4;
  int off = (kc * 64 + g * 16) ^ ((b & 7) << 4);
  return *(const bf16x8*)(base + b * 256 + off);
}
static __device__ __forceinline__ void awrite16(char* base, int b, int k, unsigned short v) {
  int off = (2 * k) ^ ((b & 7) << 4);
  *(unsigned short*)(base + b * 256 + off) = v;
}
static __device__ __forceinline__ void awrite32(char* base, int b, int k, unsigned v) {
  int off = (2 * k) ^ ((b & 7) << 4);
  *(unsigned*)(base + b * 256 + off) = v;
}

// 8 waves. Weights = A-operand (rows = ghat) in VGPRs; activations = B-operand (cols = batch)
// in LDS; in-register cell update (C/D rows = the 4 gates of a unit).
// Encoder: 1 barrier/step; iter t reads ALL frags from buf[t&1^1] (h(t-1) + x(t+1)) and
// writes ALL to buf[t&1] (h(t) + staged x(t+2)); xg(t+1) computed during step t as
// independent MFMA chains -> 8 indep 3-chains/wave/iter.
// Phase 2: lagged pipeline (latent t=i | decoder t=i-1 | projection t=i-2), 1 barrier/iter,
// 9 indep 3-chains/wave/iter.
extern "C" __global__ __launch_bounds__(512, 2)
void lstm_ae_mfma4(const float* __restrict__ x,
                   const float* __restrict__ eWih, const float* __restrict__ eWhh, const float* __restrict__ eb,
                   const float* __restrict__ lWih, const float* __restrict__ lWhh, const float* __restrict__ lb,
                   const float* __restrict__ dWih, const float* __restrict__ dWhh, const float* __restrict__ db,
                   const float* __restrict__ oW,  const float* __restrict__ ob,
                   float* __restrict__ out)
{
  __shared__ __align__(16) char sAhi[2][4096];
  __shared__ __align__(16) char sAlo[2][4096];

  const int tid  = threadIdx.x;
  const int lane = tid & 63;
  const int w    = tid >> 6;        // wave 0..7
  const int c16  = lane & 15;       // batch
  const int p4   = lane >> 4;
  const int bbase = blockIdx.x * 16;

  // ---------- zero both buffers ----------
  {
    f32x4 z = {0.f, 0.f, 0.f, 0.f};
    *(f32x4*)(&sAhi[0][0] + tid * 16) = z;
    *(f32x4*)(&sAlo[0][0] + tid * 16) = z;
  }

  // ---------- encoder weights: rows tr=c16 -> (u = w*8+(tr>>2)*2+n, ga = tr&3) ----------
  // k: 0..39 = x (chunks 0,1), 64..127 = h_enc slot 64+u (chunks 2,3)
  bf16x8 ewh[2][4], ewl[2][4];
  float ebias[2][4];
#pragma unroll
  for (int n = 0; n < 2; ++n) {
    int tr = c16;
    int u = w * 8 + (tr >> 2) * 2 + n;
    int ga = tr & 3;
#pragma unroll
    for (int r = 0; r < 4; ++r) ebias[n][r] = eb[r * 64 + (w * 8 + p4 * 2 + n)];
#pragma unroll
    for (int kc = 0; kc < 4; ++kc) {
      bf16x8 hi, lo;
#pragma unroll
      for (int e = 0; e < 8; ++e) {
        int k = kc * 32 + p4 * 8 + e;
        float v = 0.f;
        if (k < 40)       v = eWih[(ga * 64 + u) * 40 + k];
        else if (k >= 64) v = eWhh[(ga * 64 + u) * 64 + (k - 64)];
        unsigned short hh = f2bf(v);
        hi[e] = (short)hh;
        lo[e] = (short)f2bf(v - bf2f(hh));
      }
      ewh[n][kc] = hi; ewl[n][kc] = lo;
    }
  }

  __syncthreads();  // zeros visible before staging overwrites parts

  // ---------- stage x(0) -> buf0, x(1) -> buf1 ----------
  if (tid < 320) {
    int s = (tid < 160) ? tid : tid - 160;
    int buf = (tid < 160) ? 0 : 1;
    int b = s / 10, f4 = s - b * 10;
    f32x4 ld = *(const f32x4*)(x + ((size_t)(bbase + b) * 100 + buf) * 40 + f4 * 4);
    unsigned long long ph = 0, pl = 0;
#pragma unroll
    for (int e = 0; e < 4; ++e) {
      unsigned short hh = f2bf(ld[e]);
      unsigned short ll = f2bf(ld[e] - bf2f(hh));
      ph |= (unsigned long long)hh << (16 * e);
      pl |= (unsigned long long)ll << (16 * e);
    }
    int off = (f4 * 8) ^ ((b & 7) << 4);
    *(unsigned long long*)(sAhi[buf] + b * 256 + off) = ph;
    *(unsigned long long*)(sAlo[buf] + b * 256 + off) = pl;
  }
  __syncthreads();

  // ---------- xg(0) = ebias + Wih·x(0) (from buf0) ----------
  f32x4 xg[2];
  {
    bf16x8 x0h = aread(sAhi[0], lane, 0), x0l = aread(sAlo[0], lane, 0);
    bf16x8 x1h = aread(sAhi[0], lane, 1), x1l = aread(sAlo[0], lane, 1);
#pragma unroll
    for (int n = 0; n < 2; ++n) {
      f32x4 a = f32x4{ebias[n][0], ebias[n][1], ebias[n][2], ebias[n][3]};
      a = MFMA(ewh[n][0], x0h, a);
      a = MFMA(ewl[n][0], x0h, a);
      a = MFMA(ewh[n][0], x0l, a);
      f32x4 b = f32x4{0.f, 0.f, 0.f, 0.f};
      b = MFMA(ewh[n][1], x1h, b);
      b = MFMA(ewl[n][1], x1h, b);
      b = MFMA(ewh[n][1], x1l, b);
      xg[n] = a + b;
    }
  }
  __syncthreads();  // buf0 x-chunk reads complete before iter-0 stager overwrites

  float cE[2] = {0.f, 0.f};

  // ================= PHASE 1: encoder, 1 barrier/step =================
#pragma unroll 1
  for (int t = 0; t < 100; ++t) {
    const int cb = t & 1;
    const char* Rh = sAhi[cb ^ 1];
    const char* Rl = sAlo[cb ^ 1];
    char* Wh = sAhi[cb];
    char* Wl = sAlo[cb];

    // reads: x(t+1) chunks 0,1; h(t-1) chunks 2,3 — all from R
    bf16x8 x0h = aread(Rh, lane, 0), x0l = aread(Rl, lane, 0);
    bf16x8 x1h = aread(Rh, lane, 1), x1l = aread(Rl, lane, 1);
    bf16x8 h2h = aread(Rh, lane, 2), h2l = aread(Rl, lane, 2);
    bf16x8 h3h = aread(Rh, lane, 3), h3l = aread(Rl, lane, 3);

    // stager: issue x(t+2) global load early
    f32x4 xld;
    const bool stager = (tid < 160) && (t + 2 < 100);
    int sb = tid / 10, sf4 = tid - sb * 10;
    if (stager)
      xld = *(const f32x4*)(x + ((size_t)(bbase + sb) * 100 + (t + 2)) * 40 + sf4 * 4);

    // 8 independent 3-MFMA chains
    f32x4 xnA[2], xnB[2], haA[2], haB[2];
#pragma unroll
    for (int n = 0; n < 2; ++n) {
      haA[n] = xg[n];
      haA[n] = MFMA(ewh[n][2], h2h, haA[n]);
      haA[n] = MFMA(ewl[n][2], h2h, haA[n]);
      haA[n] = MFMA(ewh[n][2], h2l, haA[n]);
      haB[n] = f32x4{0.f, 0.f, 0.f, 0.f};
      haB[n] = MFMA(ewh[n][3], h3h, haB[n]);
      haB[n] = MFMA(ewl[n][3], h3h, haB[n]);
      haB[n] = MFMA(ewh[n][3], h3l, haB[n]);
      xnA[n] = f32x4{ebias[n][0], ebias[n][1], ebias[n][2], ebias[n][3]};
      xnA[n] = MFMA(ewh[n][0], x0h, xnA[n]);
      xnA[n] = MFMA(ewl[n][0], x0h, xnA[n]);
      xnA[n] = MFMA(ewh[n][0], x0l, xnA[n]);
      xnB[n] = f32x4{0.f, 0.f, 0.f, 0.f};
      xnB[n] = MFMA(ewh[n][1], x1h, xnB[n]);
      xnB[n] = MFMA(ewl[n][1], x1h, xnB[n]);
      xnB[n] = MFMA(ewh[n][1], x1l, xnB[n]);
    }

    // cell update (gates = haA+haB), h(t) -> W chunks 2,3
    unsigned short hh[2], hl[2];
#pragma unroll
    for (int n = 0; n < 2; ++n) {
      f32x4 gv = haA[n] + haB[n];
      float ii = fast_sig(gv[0]), ff = fast_sig(gv[1]);
      float gg = fast_tanh(gv[2]), oo = fast_sig(gv[3]);
      cE[n] = ff * cE[n] + ii * gg;
      float hv = oo * fast_tanh(cE[n]);
      hh[n] = f2bf(hv);
      hl[n] = f2bf(hv - bf2f(hh[n]));
      xg[n] = xnA[n] + xnB[n];   // xg(t+1)
    }
    awrite32(Wh, c16, 64 + w * 8 + p4 * 2, (unsigned)hh[0] | ((unsigned)hh[1] << 16));
    awrite32(Wl, c16, 64 + w * 8 + p4 * 2, (unsigned)hl[0] | ((unsigned)hl[1] << 16));

    // stager: convert + write x(t+2) -> W chunks 0,1
    if (stager) {
      unsigned long long ph = 0, pl = 0;
#pragma unroll
      for (int e = 0; e < 4; ++e) {
        unsigned short hhx = f2bf(xld[e]);
        unsigned short llx = f2bf(xld[e] - bf2f(hhx));
        ph |= (unsigned long long)hhx << (16 * e);
        pl |= (unsigned long long)llx << (16 * e);
      }
      int off = (sf4 * 8) ^ ((sb & 7) << 4);
      *(unsigned long long*)(Wh + sb * 256 + off) = ph;
      *(unsigned long long*)(Wl + sb * 256 + off) = pl;
    }
    __syncthreads();
  }

  // ================= xg_lat = lb + lWih @ h_enc_last (h(99) in buf1 chunks 2,3) =================
  f32x4 xga;
  {
    int tr = c16;
    int u = w * 4 + (tr >> 2), ga = tr & 3;
    int ul = w * 4 + p4;
    xga = f32x4{lb[ul], lb[32 + ul], lb[64 + ul], lb[96 + ul]};
#pragma unroll
    for (int kci = 0; kci < 2; ++kci) {
      bf16x8 hi, lo;
#pragma unroll
      for (int e = 0; e < 8; ++e) {
        float v = lWih[(ga * 32 + u) * 64 + kci * 32 + p4 * 8 + e];
        unsigned short hh = f2bf(v);
        hi[e] = (short)hh;
        lo[e] = (short)f2bf(v - bf2f(hh));
      }
      bf16x8 ah = aread(sAhi[1], lane, 2 + kci);
      bf16x8 al = aread(sAlo[1], lane, 2 + kci);
      xga = MFMA(hi, ah, xga);
      xga = MFMA(lo, ah, xga);
      xga = MFMA(hi, al, xga);
    }
  }
  __syncthreads();  // done reading h_enc

  // re-zero both buffers (h_lat(-1) = h_dec(-1) = h_dec(-2) = 0)
  {
    f32x4 z = {0.f, 0.f, 0.f, 0.f};
    *(f32x4*)(&sAhi[0][0] + tid * 16) = z;
    *(f32x4*)(&sAlo[0][0] + tid * 16) = z;
  }

  // ---------- phase-2 weights ----------
  bf16x8 lwh, lwl;
  {
    int tr = c16;
    int u = w * 4 + (tr >> 2), ga = tr & 3;
    bf16x8 hi, lo;
#pragma unroll
    for (int e = 0; e < 8; ++e) {
      float v = lWhh[(ga * 32 + u) * 32 + p4 * 8 + e];
      unsigned short hh = f2bf(v);
      hi[e] = (short)hh;
      lo[e] = (short)f2bf(v - bf2f(hh));
    }
    lwh = hi; lwl = lo;
  }
  bf16x8 dwh[2][3], dwl[2][3];
  float dbias[2][4];
#pragma unroll
  for (int n = 0; n < 2; ++n) {
    int tr = c16;
    int u = w * 8 + (tr >> 2) * 2 + n;
    int ga = tr & 3;
#pragma unroll
    for (int r = 0; r < 4; ++r) dbias[n][r] = db[r * 64 + (w * 8 + p4 * 2 + n)];
#pragma unroll
    for (int kc = 0; kc < 3; ++kc) {
      bf16x8 hi, lo;
#pragma unroll
      for (int e = 0; e < 8; ++e) {
        int k = kc * 32 + p4 * 8 + e;
        float v = (k < 32) ? dWih[(ga * 64 + u) * 32 + k]
                           : dWhh[(ga * 64 + u) * 64 + (k - 32)];
        unsigned short hh = f2bf(v);
        hi[e] = (short)hh;
        lo[e] = (short)f2bf(v - bf2f(hh));
      }
      dwh[n][kc] = hi; dwl[n][kc] = lo;
    }
  }
  bf16x8 pwh[2], pwl[2];
  float pbias[4];
#pragma unroll
  for (int r = 0; r < 4; ++r) {
    int f = w * 16 + p4 * 4 + r;
    pbias[r] = (w < 3 && f < 40) ? ob[f] : 0.0f;
  }
  if (w < 3) {
    int f = w * 16 + c16;
#pragma unroll
    for (int kci = 0; kci < 2; ++kci) {
      bf16x8 hi, lo;
#pragma unroll
      for (int e = 0; e < 8; ++e) {
        float v = (f < 40) ? oW[f * 64 + kci * 32 + p4 * 8 + e] : 0.0f;
        unsigned short hh = f2bf(v);
        hi[e] = (short)hh;
        lo[e] = (short)f2bf(v - bf2f(hh));
      }
      pwh[kci] = hi; pwl[kci] = lo;
    }
  }

  float cL = 0.f;
  float cD[2] = {0.f, 0.f};
  __syncthreads();

  // ================= PHASE 2: lagged pipeline, 1 barrier/iter =================
  // iter i: latent t=i | decoder t=i-1 | projection t=i-2.
  // h_lat(t) -> buf[t&1] k 0..31; h_dec(t) -> buf[t&1] k 32..95.
#pragma unroll 1
  for (int i = 0; i < 102; ++i) {
    const int pa = i & 1;
    bf16x8 c0h = aread(sAhi[pa ^ 1], lane, 0), c0l = aread(sAlo[pa ^ 1], lane, 0);
    bf16x8 d1h = aread(sAhi[pa], lane, 1),     d1l = aread(sAlo[pa], lane, 1);
    bf16x8 d2h = aread(sAhi[pa], lane, 2),     d2l = aread(sAlo[pa], lane, 2);

    // --- latent step t=i (reads h_lat(i-1) = c0) ---
    if (i < 100) {
      f32x4 lac = xga;
      lac = MFMA(lwh, c0h, lac);
      lac = MFMA(lwl, c0h, lac);
      lac = MFMA(lwh, c0l, lac);
      float ii = fast_sig(lac[0]), ff = fast_sig(lac[1]);
      float gg = fast_tanh(lac[2]), oo = fast_sig(lac[3]);
      cL = ff * cL + ii * gg;
      float hv = oo * fast_tanh(cL);
      unsigned short hhh = f2bf(hv);
      awrite16(sAhi[pa], c16, w * 4 + p4, hhh);
      awrite16(sAlo[pa], c16, w * 4 + p4, f2bf(hv - bf2f(hhh)));
    }

    // --- decoder step t=i-1: 3 indep chains per n ---
    if (i >= 1 && i < 101) {
      unsigned short hh[2], hl[2];
#pragma unroll
      for (int n = 0; n < 2; ++n) {
        f32x4 dA = f32x4{dbias[n][0], dbias[n][1], dbias[n][2], dbias[n][3]};
        dA = MFMA(dwh[n][0], c0h, dA);
        dA = MFMA(dwl[n][0], c0h, dA);
        dA = MFMA(dwh[n][0], c0l, dA);
        f32x4 dB = f32x4{0.f, 0.f, 0.f, 0.f};
        dB = MFMA(dwh[n][1], d1h, dB);
        dB = MFMA(dwl[n][1], d1h, dB);
        dB = MFMA(dwh[n][1], d1l, dB);
        f32x4 dC = f32x4{0.f, 0.f, 0.f, 0.f};
        dC = MFMA(dwh[n][2], d2h, dC);
        dC = MFMA(dwl[n][2], d2h, dC);
        dC = MFMA(dwh[n][2], d2l, dC);
        f32x4 gv = (dA + dB) + dC;
        float ii = fast_sig(gv[0]), ff = fast_sig(gv[1]);
        float gg = fast_tanh(gv[2]), oo = fast_sig(gv[3]);
        cD[n] = ff * cD[n] + ii * gg;
        float hv = oo * fast_tanh(cD[n]);
        hh[n] = f2bf(hv);
        hl[n] = f2bf(hv - bf2f(hh[n]));
      }
      awrite32(sAhi[pa ^ 1], c16, 32 + w * 8 + p4 * 2, (unsigned)hh[0] | ((unsigned)hh[1] << 16));
      awrite32(sAlo[pa ^ 1], c16, 32 + w * 8 + p4 * 2, (unsigned)hl[0] | ((unsigned)hl[1] << 16));
    }

    // --- projection t=i-2: 2 indep chains ---
    if (i >= 2 && w < 3) {
      f32x4 pA = f32x4{pbias[0], pbias[1], pbias[2], pbias[3]};
      pA = MFMA(pwh[0], d1h, pA);
      pA = MFMA(pwl[0], d1h, pA);
      pA = MFMA(pwh[0], d1l, pA);
      f32x4 pB = f32x4{0.f, 0.f, 0.f, 0.f};
      pB = MFMA(pwh[1], d2h, pB);
      pB = MFMA(pwl[1], d2h, pB);
      pB = MFMA(pwh[1], d2l, pB);
      f32x4 pac = pA + pB;
#pragma unroll
      for (int r = 0; r < 4; ++r) {
        int f = w * 16 + p4 * 4 + r;
        if (f < 40)
          out[((size_t)(bbase + c16) * 100 + (i - 2)) * 40 + f] = pac[r];
      }
    }
    __syncthreads();
  }
}

extern "C" void kernel_launch(void* const* d_in, const int* in_sizes, int n_in,
                              void* d_out, int out_size, void* d_ws, size_t ws_size,
                              hipStream_t stream) {
  const float* x    = (const float*)d_in[0];
  const float* eWih = (const float*)d_in[1];
  const float* eWhh = (const float*)d_in[2];
  const float* eb   = (const float*)d_in[3];
  const float* lWih = (const float*)d_in[4];
  const float* lWhh = (const float*)d_in[5];
  const float* lb   = (const float*)d_in[6];
  const float* dWih = (const float*)d_in[7];
  const float* dWhh = (const float*)d_in[8];
  const float* db   = (const float*)d_in[9];
  const float* oW   = (const float*)d_in[10];
  const float* ob   = (const float*)d_in[11];
  float* out = (float*)d_out;

  lstm_ae_mfma4<<<256, 512, 0, stream>>>(x, eWih, eWhh, eb, lWih, lWhh, lb,
                                         dWih, dWhh, db, oW, ob, out);
}

// Round 6
// 184.084 us; speedup vs baseline: 1.0811x; 1.0811x over previous
//
#include <hip/hip_runtime.h>
#include <cstddef>

typedef __attribute__((ext_vector_type(8))) short bf16x8;
typedef __attribute__((ext_vector_type(4))) float f32x4;

#define MFMA(a, b, c) __builtin_amdgcn_mfma_f32_16x16x32_bf16((a), (b), (c), 0, 0, 0)

static __device__ __forceinline__ unsigned short f2bf(float f) {
  unsigned u = __builtin_bit_cast(unsigned, f);
  u = u + 0x7FFFu + ((u >> 16) & 1u);
  return (unsigned short)(u >> 16);
}
static __device__ __forceinline__ float bf2f(unsigned short h) {
  unsigned u = ((unsigned)h) << 16;
  return __builtin_bit_cast(float, u);
}
static __device__ __forceinline__ float fast_sig(float x) {
  return __builtin_amdgcn_rcpf(1.0f + __expf(-x));
}
static __device__ __forceinline__ float fast_tanh(float x) {
  return 2.0f * __builtin_amdgcn_rcpf(1.0f + __expf(-2.0f * x)) - 1.0f;
}

// LDS-only barrier: orders LDS writes across waves WITHOUT draining vmcnt.
// __syncthreads() would emit s_waitcnt vmcnt(0) -> forces global out-stores /
// in-flight prefetch loads to complete every iteration. We only need lgkmcnt.
static __device__ __forceinline__ void lds_barrier() {
  asm volatile("s_waitcnt lgkmcnt(0)\n\ts_barrier" ::: "memory");
}

// Activation buffer: [16 batch rows][256 B = 128 bf16 k-slots], XOR-swizzled per row.
// B-fragment (cols = batch): lane holds col b=lane&15, k = kc*32 + (lane>>4)*8 + {0..7}.
static __device__ __forceinline__ bf16x8 aread(const char* base, int lane, int kc) {
  int b = lane & 15, g = lane >> 4;
  int off = (kc * 64 + g * 16) ^ ((b & 7) << 4);
  return *(const bf16x8*)(base + b * 256 + off);
}
static __device__ __forceinline__ void awrite16(char* base, int b, int k, unsigned short v) {
  int off = (2 * k) ^ ((b & 7) << 4);
  *(unsigned short*)(base + b * 256 + off) = v;
}
static __device__ __forceinline__ void awrite32(char* base, int b, int k, unsigned v) {
  int off = (2 * k) ^ ((b & 7) << 4);
  *(unsigned*)(base + b * 256 + off) = v;
}

// 8 waves. Weights = A-operand (rows = ghat) in VGPRs; activations = B-operand
// (cols = batch) in LDS; in-register cell update (C/D rows = 4 gates of a unit).
// Encoder: iter t reads buf[t&1] (x(t) ch0,1 + h(t-1) ch2,3), writes buf[t&1^1]
// (h(t) ch2,3 + x(t+1) ch0,1 from regs loaded at iter t-1  -> depth-2 prefetch,
// load stays in flight across the raw barrier). 1 lds_barrier/step.
// Phase 2: lagged pipeline (latent t=i | decoder t=i-1 | projection t=i-2),
// 1 lds_barrier/iter, out-stores never drained at barriers.
extern "C" __global__ __launch_bounds__(512, 2)
void lstm_ae_mfma5(const float* __restrict__ x,
                   const float* __restrict__ eWih, const float* __restrict__ eWhh, const float* __restrict__ eb,
                   const float* __restrict__ lWih, const float* __restrict__ lWhh, const float* __restrict__ lb,
                   const float* __restrict__ dWih, const float* __restrict__ dWhh, const float* __restrict__ db,
                   const float* __restrict__ oW,  const float* __restrict__ ob,
                   float* __restrict__ out)
{
  __shared__ __align__(16) char sAhi[2][4096];
  __shared__ __align__(16) char sAlo[2][4096];

  const int tid  = threadIdx.x;
  const int lane = tid & 63;
  const int w    = tid >> 6;        // wave 0..7
  const int c16  = lane & 15;       // batch
  const int p4   = lane >> 4;
  const int bbase = blockIdx.x * 16;

  // ---------- zero both buffers ----------
  {
    f32x4 z = {0.f, 0.f, 0.f, 0.f};
    *(f32x4*)(&sAhi[0][0] + tid * 16) = z;
    *(f32x4*)(&sAlo[0][0] + tid * 16) = z;
  }

  // ---------- encoder weights: rows tr=c16 -> (u = w*8+(tr>>2)*2+n, ga = tr&3) ----------
  // k: 0..39 = x (chunks 0,1), 64..127 = h_enc slot 64+u (chunks 2,3)
  bf16x8 ewh[2][4], ewl[2][4];
  float ebias[2][4];
#pragma unroll
  for (int n = 0; n < 2; ++n) {
    int tr = c16;
    int u = w * 8 + (tr >> 2) * 2 + n;
    int ga = tr & 3;
#pragma unroll
    for (int r = 0; r < 4; ++r) ebias[n][r] = eb[r * 64 + (w * 8 + p4 * 2 + n)];
#pragma unroll
    for (int kc = 0; kc < 4; ++kc) {
      bf16x8 hi, lo;
#pragma unroll
      for (int e = 0; e < 8; ++e) {
        int k = kc * 32 + p4 * 8 + e;
        float v = 0.f;
        if (k < 40)       v = eWih[(ga * 64 + u) * 40 + k];
        else if (k >= 64) v = eWhh[(ga * 64 + u) * 64 + (k - 64)];
        unsigned short hh = f2bf(v);
        hi[e] = (short)hh;
        lo[e] = (short)f2bf(v - bf2f(hh));
      }
      ewh[n][kc] = hi; ewl[n][kc] = lo;
    }
  }

  lds_barrier();  // zeros visible before staging overwrites x-chunks

  // ---------- stage x(0) -> buf0 directly; preload x(1) into regs ----------
  const bool stager = (tid < 160);
  const int sb = tid / 10, sf4 = tid - (tid / 10) * 10;
  if (stager) {
    f32x4 ld = *(const f32x4*)(x + ((size_t)(bbase + sb) * 100 + 0) * 40 + sf4 * 4);
    unsigned long long ph = 0, pl = 0;
#pragma unroll
    for (int e = 0; e < 4; ++e) {
      unsigned short hh = f2bf(ld[e]);
      unsigned short ll = f2bf(ld[e] - bf2f(hh));
      ph |= (unsigned long long)hh << (16 * e);
      pl |= (unsigned long long)ll << (16 * e);
    }
    int off = (sf4 * 8) ^ ((sb & 7) << 4);
    *(unsigned long long*)(sAhi[0] + sb * 256 + off) = ph;
    *(unsigned long long*)(sAlo[0] + sb * 256 + off) = pl;
  }
  f32x4 xldA = {0.f, 0.f, 0.f, 0.f}, xldB = {0.f, 0.f, 0.f, 0.f};
  if (stager)
    xldA = *(const f32x4*)(x + ((size_t)(bbase + sb) * 100 + 1) * 40 + sf4 * 4);

  float cE[2] = {0.f, 0.f};
  lds_barrier();

  // ================= PHASE 1: encoder, 1 lds_barrier/step =================
  auto enc_step = [&](int t, const char* Rh, const char* Rl, char* Wh, char* Wl,
                      f32x4& xin, f32x4& xout) {
    // (1) convert + write x(t+1) = xin -> W chunks 0,1 (loaded one iter ago; ~no vmcnt stall)
    if (stager) {
      unsigned long long ph = 0, pl = 0;
#pragma unroll
      for (int e = 0; e < 4; ++e) {
        unsigned short hh = f2bf(xin[e]);
        unsigned short ll = f2bf(xin[e] - bf2f(hh));
        ph |= (unsigned long long)hh << (16 * e);
        pl |= (unsigned long long)ll << (16 * e);
      }
      int off = (sf4 * 8) ^ ((sb & 7) << 4);
      *(unsigned long long*)(Wh + sb * 256 + off) = ph;
      *(unsigned long long*)(Wl + sb * 256 + off) = pl;
      // (2) issue load x(t+2) -> xout; stays in flight across the barrier
      int tn = (t + 2 <= 99) ? t + 2 : 99;
      xout = *(const f32x4*)(x + ((size_t)(bbase + sb) * 100 + tn) * 40 + sf4 * 4);
    }

    // (3) MFMA: gates(t) = bias + Wih·x(t) + Whh·h(t-1), all frags from R
    f32x4 acc[2], acc2[2];
#pragma unroll
    for (int n = 0; n < 2; ++n) {
      acc[n]  = f32x4{ebias[n][0], ebias[n][1], ebias[n][2], ebias[n][3]};
      acc2[n] = f32x4{0.f, 0.f, 0.f, 0.f};
    }
#pragma unroll
    for (int kc = 0; kc < 4; ++kc) {
      bf16x8 ah = aread(Rh, lane, kc);
      bf16x8 al = aread(Rl, lane, kc);
#pragma unroll
      for (int n = 0; n < 2; ++n) {
        f32x4 t0 = (kc < 2) ? acc[n] : acc2[n];
        t0 = MFMA(ewh[n][kc], ah, t0);
        t0 = MFMA(ewl[n][kc], ah, t0);
        t0 = MFMA(ewh[n][kc], al, t0);
        if (kc < 2) acc[n] = t0; else acc2[n] = t0;
      }
    }

    // (4) cell update, h(t) -> W chunks 2,3
    unsigned short hh[2], hl[2];
#pragma unroll
    for (int n = 0; n < 2; ++n) {
      f32x4 gv = acc[n] + acc2[n];
      float ii = fast_sig(gv[0]), ff = fast_sig(gv[1]);
      float gg = fast_tanh(gv[2]), oo = fast_sig(gv[3]);
      cE[n] = ff * cE[n] + ii * gg;
      float hv = oo * fast_tanh(cE[n]);
      hh[n] = f2bf(hv);
      hl[n] = f2bf(hv - bf2f(hh[n]));
    }
    awrite32(Wh, c16, 64 + w * 8 + p4 * 2, (unsigned)hh[0] | ((unsigned)hh[1] << 16));
    awrite32(Wl, c16, 64 + w * 8 + p4 * 2, (unsigned)hl[0] | ((unsigned)hl[1] << 16));

    lds_barrier();
  };

#pragma unroll 1
  for (int tt = 0; tt < 100; tt += 2) {
    enc_step(tt,     sAhi[0], sAlo[0], sAhi[1], sAlo[1], xldA, xldB);
    enc_step(tt + 1, sAhi[1], sAlo[1], sAhi[0], sAlo[0], xldB, xldA);
  }
  // h(99) was written by iter 99 into W = buf0 chunks 2,3.

  // ================= xg_lat = lb + lWih @ h_enc_last =================
  f32x4 xga;
  {
    int tr = c16;
    int u = w * 4 + (tr >> 2), ga = tr & 3;
    int ul = w * 4 + p4;
    xga = f32x4{lb[ul], lb[32 + ul], lb[64 + ul], lb[96 + ul]};
#pragma unroll
    for (int kci = 0; kci < 2; ++kci) {
      bf16x8 hi, lo;
#pragma unroll
      for (int e = 0; e < 8; ++e) {
        float v = lWih[(ga * 32 + u) * 64 + kci * 32 + p4 * 8 + e];
        unsigned short hh = f2bf(v);
        hi[e] = (short)hh;
        lo[e] = (short)f2bf(v - bf2f(hh));
      }
      bf16x8 ah = aread(sAhi[0], lane, 2 + kci);
      bf16x8 al = aread(sAlo[0], lane, 2 + kci);
      xga = MFMA(hi, ah, xga);
      xga = MFMA(lo, ah, xga);
      xga = MFMA(hi, al, xga);
    }
  }
  lds_barrier();  // all reads of h_enc complete before re-zero

  // re-zero both buffers (h_lat(-1) = h_dec(-1) = h_dec(-2) = 0)
  {
    f32x4 z = {0.f, 0.f, 0.f, 0.f};
    *(f32x4*)(&sAhi[0][0] + tid * 16) = z;
    *(f32x4*)(&sAlo[0][0] + tid * 16) = z;
  }

  // ---------- phase-2 weights ----------
  bf16x8 lwh, lwl;
  {
    int tr = c16;
    int u = w * 4 + (tr >> 2), ga = tr & 3;
    bf16x8 hi, lo;
#pragma unroll
    for (int e = 0; e < 8; ++e) {
      float v = lWhh[(ga * 32 + u) * 32 + p4 * 8 + e];
      unsigned short hh = f2bf(v);
      hi[e] = (short)hh;
      lo[e] = (short)f2bf(v - bf2f(hh));
    }
    lwh = hi; lwl = lo;
  }
  bf16x8 dwh[2][3], dwl[2][3];
  float dbias[2][4];
#pragma unroll
  for (int n = 0; n < 2; ++n) {
    int tr = c16;
    int u = w * 8 + (tr >> 2) * 2 + n;
    int ga = tr & 3;
#pragma unroll
    for (int r = 0; r < 4; ++r) dbias[n][r] = db[r * 64 + (w * 8 + p4 * 2 + n)];
#pragma unroll
    for (int kc = 0; kc < 3; ++kc) {
      bf16x8 hi, lo;
#pragma unroll
      for (int e = 0; e < 8; ++e) {
        int k = kc * 32 + p4 * 8 + e;
        float v = (k < 32) ? dWih[(ga * 64 + u) * 32 + k]
                           : dWhh[(ga * 64 + u) * 64 + (k - 32)];
        unsigned short hh = f2bf(v);
        hi[e] = (short)hh;
        lo[e] = (short)f2bf(v - bf2f(hh));
      }
      dwh[n][kc] = hi; dwl[n][kc] = lo;
    }
  }
  bf16x8 pwh[2], pwl[2];
  float pbias[4];
#pragma unroll
  for (int r = 0; r < 4; ++r) {
    int f = w * 16 + p4 * 4 + r;
    pbias[r] = (w < 3 && f < 40) ? ob[f] : 0.0f;
  }
  if (w < 3) {
    int f = w * 16 + c16;
#pragma unroll
    for (int kci = 0; kci < 2; ++kci) {
      bf16x8 hi, lo;
#pragma unroll
      for (int e = 0; e < 8; ++e) {
        float v = (f < 40) ? oW[f * 64 + kci * 32 + p4 * 8 + e] : 0.0f;
        unsigned short hh = f2bf(v);
        hi[e] = (short)hh;
        lo[e] = (short)f2bf(v - bf2f(hh));
      }
      pwh[kci] = hi; pwl[kci] = lo;
    }
  }

  float cL = 0.f;
  float cD[2] = {0.f, 0.f};
  lds_barrier();

  // ================= PHASE 2: lagged pipeline, 1 lds_barrier/iter =================
  // iter i: latent t=i | decoder t=i-1 | projection t=i-2.
  // h_lat(t) -> buf[t&1] k 0..31; h_dec(t) -> buf[t&1] k 32..95.
#pragma unroll 1
  for (int i = 0; i < 102; ++i) {
    const int pa = i & 1;
    bf16x8 c0h = aread(sAhi[pa ^ 1], lane, 0), c0l = aread(sAlo[pa ^ 1], lane, 0);
    bf16x8 d1h = aread(sAhi[pa], lane, 1),     d1l = aread(sAlo[pa], lane, 1);
    bf16x8 d2h = aread(sAhi[pa], lane, 2),     d2l = aread(sAlo[pa], lane, 2);

    // --- latent step t=i (reads h_lat(i-1) = c0) ---
    if (i < 100) {
      f32x4 lac = xga;
      lac = MFMA(lwh, c0h, lac);
      lac = MFMA(lwl, c0h, lac);
      lac = MFMA(lwh, c0l, lac);
      float ii = fast_sig(lac[0]), ff = fast_sig(lac[1]);
      float gg = fast_tanh(lac[2]), oo = fast_sig(lac[3]);
      cL = ff * cL + ii * gg;
      float hv = oo * fast_tanh(cL);
      unsigned short hhh = f2bf(hv);
      awrite16(sAhi[pa], c16, w * 4 + p4, hhh);
      awrite16(sAlo[pa], c16, w * 4 + p4, f2bf(hv - bf2f(hhh)));
    }

    // --- decoder step t=i-1 (reads h_lat(i-1) = c0, h_dec(i-2) = d1,d2) ---
    if (i >= 1 && i < 101) {
      unsigned short hh[2], hl[2];
#pragma unroll
      for (int n = 0; n < 2; ++n) {
        f32x4 dac = f32x4{dbias[n][0], dbias[n][1], dbias[n][2], dbias[n][3]};
        dac = MFMA(dwh[n][0], c0h, dac);
        dac = MFMA(dwl[n][0], c0h, dac);
        dac = MFMA(dwh[n][0], c0l, dac);
        dac = MFMA(dwh[n][1], d1h, dac);
        dac = MFMA(dwl[n][1], d1h, dac);
        dac = MFMA(dwh[n][1], d1l, dac);
        dac = MFMA(dwh[n][2], d2h, dac);
        dac = MFMA(dwl[n][2], d2h, dac);
        dac = MFMA(dwh[n][2], d2l, dac);
        float ii = fast_sig(dac[0]), ff = fast_sig(dac[1]);
        float gg = fast_tanh(dac[2]), oo = fast_sig(dac[3]);
        cD[n] = ff * cD[n] + ii * gg;
        float hv = oo * fast_tanh(cD[n]);
        hh[n] = f2bf(hv);
        hl[n] = f2bf(hv - bf2f(hh[n]));
      }
      awrite32(sAhi[pa ^ 1], c16, 32 + w * 8 + p4 * 2, (unsigned)hh[0] | ((unsigned)hh[1] << 16));
      awrite32(sAlo[pa ^ 1], c16, 32 + w * 8 + p4 * 2, (unsigned)hl[0] | ((unsigned)hl[1] << 16));
    }

    // --- projection t=i-2 (reads h_dec(i-2) = d1,d2; shares the reads) ---
    if (i >= 2 && w < 3) {
      f32x4 pac = f32x4{pbias[0], pbias[1], pbias[2], pbias[3]};
      pac = MFMA(pwh[0], d1h, pac);
      pac = MFMA(pwl[0], d1h, pac);
      pac = MFMA(pwh[0], d1l, pac);
      pac = MFMA(pwh[1], d2h, pac);
      pac = MFMA(pwl[1], d2h, pac);
      pac = MFMA(pwh[1], d2l, pac);
#pragma unroll
      for (int r = 0; r < 4; ++r) {
        int f = w * 16 + p4 * 4 + r;
        if (f < 40)
          out[((size_t)(bbase + c16) * 100 + (i - 2)) * 40 + f] = pac[r];
      }
    }
    lds_barrier();
  }
}

extern "C" void kernel_launch(void* const* d_in, const int* in_sizes, int n_in,
                              void* d_out, int out_size, void* d_ws, size_t ws_size,
                              hipStream_t stream) {
  const float* x    = (const float*)d_in[0];
  const float* eWih = (const float*)d_in[1];
  const float* eWhh = (const float*)d_in[2];
  const float* eb   = (const float*)d_in[3];
  const float* lWih = (const float*)d_in[4];
  const float* lWhh = (const float*)d_in[5];
  const float* lb   = (const float*)d_in[6];
  const float* dWih = (const float*)d_in[7];
  const float* dWhh = (const float*)d_in[8];
  const float* db   = (const float*)d_in[9];
  const float* oW   = (const float*)d_in[10];
  const float* ob   = (const float*)d_in[11];
  float* out = (float*)d_out;

  lstm_ae_mfma5<<<256, 512, 0, stream>>>(x, eWih, eWhh, eb, lWih, lWhh, lb,
                                         dWih, dWhh, db, oW, ob, out);
}